// Round 10
// baseline (112.310 us; speedup 1.0000x reference)
//
#include <hip/hip_runtime.h>
#include <stdint.h>

#define IN_F 2048
#define OUT_F 2048
#define N_ROWS 8192

// ---- GEMM geometry: 128x128 tile, BK=32, 4 waves (2Mx2N), 4-deep LDS,
// r2 schedule (1 barrier + counted vmcnt per K-step), 2 blocks/CU.
#define BM 128
#define BN 128
#define BK 32
#define NT (IN_F / BK)             // 64 K-steps
#define TM_TILES (N_ROWS / BM)     // 64
#define TN_TILES (OUT_F / BN)      // 16
#define NWG (TM_TILES * TN_TILES)  // 1024 = 4 passes of 2 blocks/CU
#define TILE_SHORTS (BM * BK)      // 4096 shorts = 8 KiB
#define BUF_SHORTS (2 * TILE_SHORTS)  // A+B = 16 KiB per buffer

typedef __bf16 bf16x8 __attribute__((ext_vector_type(8)));
typedef float f32x4 __attribute__((ext_vector_type(4)));
typedef unsigned short ushortx8 __attribute__((ext_vector_type(8)));

__device__ __forceinline__ unsigned short f2bf(float f) {
  unsigned u = __builtin_bit_cast(unsigned, f);
  u += 0x7FFFu + ((u >> 16) & 1u);
  return (unsigned short)(u >> 16);
}

__device__ __forceinline__ void async16(void* lds, const void* g) {
  __builtin_amdgcn_global_load_lds(
      (const __attribute__((address_space(1))) void*)(uintptr_t)g,
      (__attribute__((address_space(3))) void*)(uint32_t)(uintptr_t)lds,
      16, 0, 0);
}

__device__ __forceinline__ bf16x8 ld8(const unsigned short* p) {
  return __builtin_bit_cast(bf16x8, *reinterpret_cast<const ushortx8*>(p));
}

// ---- fused prep: blocks [0,8192) convert A fp32->bf16; [8192,10240) build Ht
__global__ __launch_bounds__(256) void k_prep(const float* __restrict__ A,
                                              unsigned short* __restrict__ Ab,
                                              const float* __restrict__ W,
                                              unsigned short* __restrict__ Ht) {
  const int bid = blockIdx.x;
  if (bid < 8192) {
    const size_t t = (size_t)bid * 256 + threadIdx.x;
    const float4* a4 = reinterpret_cast<const float4*>(A);
    float4 v0 = a4[2 * t];
    float4 v1 = a4[2 * t + 1];
    ushortx8 o;
    o[0] = f2bf(v0.x); o[1] = f2bf(v0.y); o[2] = f2bf(v0.z); o[3] = f2bf(v0.w);
    o[4] = f2bf(v1.x); o[5] = f2bf(v1.y); o[6] = f2bf(v1.z); o[7] = f2bf(v1.w);
    *reinterpret_cast<ushortx8*>(Ab + t * 8) = o;
  } else {
    // Ht[b][a] = H_perm[a][b] = s(q,c) * W[u][(q^c)*512 + v]
    const int t = (bid - 8192) * 256 + threadIdx.x;
    const int b = t >> 8;
    const int a0 = (t & 255) << 3;
    const int c = b & 3, v = b >> 2;
    ushortx8 o;
#pragma unroll
    for (int e = 0; e < 8; ++e) {
      const int a = a0 + e;
      const int q = a & 3, u = a >> 2;
      float w = W[(size_t)u * OUT_F + ((q ^ c) << 9) + v];
      if ((0x284E >> ((q << 2) | c)) & 1) w = -w;
      o[e] = f2bf(w);
    }
    *reinterpret_cast<ushortx8*>(Ht + (size_t)b * IN_F + a0) = o;
  }
}

// ---- main GEMM: C = A(bf16) @ Ht^T + bias (r2 schedule @ 128^2, 2 blk/CU) ----
__global__ __launch_bounds__(256, 2) void k_gemm(const unsigned short* __restrict__ A,
                                                 const unsigned short* __restrict__ Bt,
                                                 const float* __restrict__ bias,
                                                 float* __restrict__ C) {
  __shared__ __align__(16) unsigned short lds[4 * BUF_SHORTS];  // 64 KiB

  const int tid = threadIdx.x;
  const int lane = tid & 63;
  const int w = tid >> 6;   // wave 0..3
  const int wm = w >> 1;    // 0..1 -> rows wm*64..+64
  const int wn = w & 1;     // 0..1 -> cols wn*64..+64
  const int fr = lane & 15;
  const int g = lane >> 4;  // k-group 0..3 (8 bf16 each)

  // XCD-bijective swizzle: 1024 wgs, 128 contiguous tiles per XCD
  const int wg = blockIdx.x;
  const int swz = (wg & 7) * (NWG >> 3) + (wg >> 3);
  const int tm = swz >> 4;          // / TN_TILES
  const int tn = swz & 15;
  const int row0 = tm * BM, col0 = tn * BN;

  // ---- staging: A tile = 512 16B-chunks; thread carries chunks tid and
  // tid+256 for both A and B (4 loads/thread/stage, as in r2).
  // chunk t: row r=t>>2, 16B slot s=t&3; write-side swizzle: slot s holds
  // global k-group ga = s ^ ((r>>1)&3) (pre-swizzled GLOBAL source,
  // linear LDS dest).
  const unsigned short* srcA0;
  const unsigned short* srcA1;
  const unsigned short* srcB0;
  const unsigned short* srcB1;
  int tOff0, tOff1;
  {
    const int t0 = tid, t1 = tid + 256;
    const int r0_ = t0 >> 2, s0_ = t0 & 3, ga0 = s0_ ^ ((r0_ >> 1) & 3);
    const int r1_ = t1 >> 2, s1_ = t1 & 3, ga1 = s1_ ^ ((r1_ >> 1) & 3);
    srcA0 = A + (size_t)(row0 + r0_) * IN_F + ga0 * 8;
    srcA1 = A + (size_t)(row0 + r1_) * IN_F + ga1 * 8;
    srcB0 = Bt + (size_t)(col0 + r0_) * IN_F + ga0 * 8;
    srcB1 = Bt + (size_t)(col0 + r1_) * IN_F + ga1 * 8;
    tOff0 = t0 * 8;  // shorts
    tOff1 = t1 * 8;
  }

#define STAGE(T)                                              \
  do {                                                        \
    unsigned short* base_ = &lds[((T) & 3) * BUF_SHORTS];     \
    const int ko_ = (T) * BK;                                 \
    async16(base_ + tOff0, srcA0 + ko_);                      \
    async16(base_ + tOff1, srcA1 + ko_);                      \
    async16(base_ + TILE_SHORTS + tOff0, srcB0 + ko_);        \
    async16(base_ + TILE_SHORTS + tOff1, srcB1 + ko_);        \
  } while (0)

  // ---- fragment read offsets (shorts), read-side swizzle matches write side
  int offA[4], offB[4];
#pragma unroll
  for (int m = 0; m < 4; ++m) {
    const int r = wm * 64 + m * 16 + fr;
    offA[m] = r * BK + ((g ^ ((r >> 1) & 3)) << 3);
  }
#pragma unroll
  for (int n = 0; n < 4; ++n) {
    const int r = wn * 64 + n * 16 + fr;
    offB[n] = TILE_SHORTS + r * BK + ((g ^ ((r >> 1) & 3)) << 3);
  }

  f32x4 acc[4][4] = {};

#define MFMA_(a_, b_, c_) __builtin_amdgcn_mfma_f32_16x16x32_bf16(a_, b_, c_, 0, 0, 0)

  // prologue: 3 tiles in flight (12 loads/thread)
  STAGE(0);
  STAGE(1);
  STAGE(2);

  // Per K-step: vmcnt(N) [own stage T retired: 12 outstanding -> 8] ->
  // barrier [all retired; all waves done reading buf[(T-1)%4]] ->
  // 8 ds_reads -> STAGE(T+3) -> 16 MFMA. Cross-block overlap (2 blocks/CU)
  // fills the drain windows.
#define TILE(T, VMSTR, DOSTAGE)                                               \
  do {                                                                        \
    asm volatile("s_waitcnt vmcnt(" VMSTR ")" ::: "memory");                  \
    __builtin_amdgcn_s_barrier();                                             \
    __builtin_amdgcn_sched_barrier(0);                                        \
    const unsigned short* b_ = &lds[((T) & 3) * BUF_SHORTS];                  \
    bf16x8 bg[4], af[4];                                                      \
    _Pragma("unroll") for (int n = 0; n < 4; ++n) bg[n] = ld8(b_ + offB[n]);  \
    _Pragma("unroll") for (int m = 0; m < 4; ++m) af[m] = ld8(b_ + offA[m]);  \
    if (DOSTAGE) STAGE((T) + 3);                                              \
    __builtin_amdgcn_s_setprio(1);                                            \
    _Pragma("unroll") for (int m = 0; m < 4; ++m)                             \
      _Pragma("unroll") for (int n = 0; n < 4; ++n)                           \
        acc[m][n] = MFMA_(af[m], bg[n], acc[m][n]);                           \
    __builtin_amdgcn_s_setprio(0);                                            \
  } while (0)

#pragma unroll 1
  for (int t = 0; t < NT - 3; ++t) {
    TILE(t, "8", true);
  }
  TILE(NT - 3, "8", false);
  TILE(NT - 2, "4", false);
  TILE(NT - 1, "0", false);

#undef TILE
#undef STAGE

  // ---- epilogue: C/D layout col=lane&15, row=(lane>>4)*4+reg ----
  const int g4 = g << 2;
  float bv[4];
#pragma unroll
  for (int n = 0; n < 4; ++n) bv[n] = bias[col0 + wn * 64 + n * 16 + fr];
#pragma unroll
  for (int m = 0; m < 4; ++m) {
#pragma unroll
    for (int e = 0; e < 4; ++e) {
      const int row = row0 + wm * 64 + m * 16 + g4 + e;
      float* cp = C + (size_t)row * OUT_F + col0 + wn * 64 + fr;
#pragma unroll
      for (int n = 0; n < 4; ++n) cp[n * 16] = acc[m][n][e] + bv[n];
    }
  }
}

// ---- fallback if workspace too small: naive fp32 ----
__global__ __launch_bounds__(256) void k_naive(const float* __restrict__ A,
                                               const float* __restrict__ W,
                                               const float* __restrict__ bias,
                                               float* __restrict__ C) {
  const int idx = blockIdx.x * 256 + threadIdx.x;
  const int m = idx >> 11;
  const int b = idx & (OUT_F - 1);
  const int c = b & 3, v = b >> 2;
  float acc = 0.f;
  const float* arow = A + (size_t)m * IN_F;
  for (int a = 0; a < IN_F; ++a) {
    const int q = a & 3, u = a >> 2;
    float h = W[(size_t)u * OUT_F + ((q ^ c) << 9) + v];
    if ((0x284E >> ((q << 2) | c)) & 1) h = -h;
    acc += arow[a] * h;
  }
  C[idx] = acc + bias[b];
}

extern "C" void kernel_launch(void* const* d_in, const int* in_sizes, int n_in,
                              void* d_out, int out_size, void* d_ws, size_t ws_size,
                              hipStream_t stream) {
  (void)in_sizes; (void)n_in; (void)out_size;
  const float* inp  = (const float*)d_in[0];
  const float* w    = (const float*)d_in[1];
  const float* bias = (const float*)d_in[2];
  float* out = (float*)d_out;

  const size_t needA = (size_t)N_ROWS * IN_F * sizeof(unsigned short);  // 32 MiB
  const size_t needH = (size_t)IN_F * OUT_F * sizeof(unsigned short);   //  8 MiB
  if (ws_size < needA + needH) {
    k_naive<<<(N_ROWS * OUT_F) / 256, 256, 0, stream>>>(inp, w, bias, out);
    return;
  }

  unsigned short* Ab = (unsigned short*)d_ws;
  unsigned short* Ht = Ab + (size_t)N_ROWS * IN_F;

  k_prep<<<8192 + 2048, 256, 0, stream>>>(inp, Ab, w, Ht);
  k_gemm<<<NWG, 256, 0, stream>>>(Ab, Ht, bias, out);
}

// Round 11
// 86.666 us; speedup vs baseline: 1.2959x; 1.2959x over previous
//
#include <hip/hip_runtime.h>
#include <stdint.h>

#define IN_F 2048
#define OUT_F 2048
#define N_ROWS 8192

// ---- GEMM geometry: 256x256 tile, BK=32, 8 waves (2Mx4N), 4-deep LDS,
// r2 schedule. NEW: A and B are pre-tiled by k_prep into the exact LDS
// image (16 KB per (tile, K-step), swizzle baked in) so every
// global_load_lds reads 1 KB fully contiguous (TA-coalesced).
#define BM 256
#define BN 256
#define BK 32
#define NT (IN_F / BK)             // 64 K-steps
#define TM_TILES (N_ROWS / BM)     // 32
#define TN_TILES (OUT_F / BN)      // 8
#define NWG (TM_TILES * TN_TILES)  // 256 == #CUs
#define TILE_SHORTS (BM * BK)      // 8192 shorts = 16 KiB per (tile,kstep)
#define BUF_SHORTS (2 * TILE_SHORTS)

typedef __bf16 bf16x8 __attribute__((ext_vector_type(8)));
typedef float f32x4 __attribute__((ext_vector_type(4)));
typedef unsigned short ushortx8 __attribute__((ext_vector_type(8)));

__device__ __forceinline__ unsigned short f2bf(float f) {
  unsigned u = __builtin_bit_cast(unsigned, f);
  u += 0x7FFFu + ((u >> 16) & 1u);
  return (unsigned short)(u >> 16);
}

__device__ __forceinline__ void async16(void* lds, const void* g) {
  __builtin_amdgcn_global_load_lds(
      (const __attribute__((address_space(1))) void*)(uintptr_t)g,
      (__attribute__((address_space(3))) void*)(uint32_t)(uintptr_t)lds,
      16, 0, 0);
}

__device__ __forceinline__ bf16x8 ld8(const unsigned short* p) {
  return __builtin_bit_cast(bf16x8, *reinterpret_cast<const ushortx8*>(p));
}

// ---- prep: build pre-tiled, pre-swizzled staging images.
// Chunk t in [0,1024) of tile (X*64+T): row r=t>>2, slot s=t&3 holds
// k-group ga = s ^ ((r>>1)&3)  (same swizzle the GEMM reads with).
// A-image: AbT[tile*8192 + t*8 + j] = bf16(A[R*256 + r][T*32 + ga*8 + j])
// B-image: BtT[tile*8192 + t*8 + j] = Ht[Ct*256 + r][T*32 + ga*8 + j],
//          Ht[b][a] = s(q,c) * W[u][(q^c)*512 + v]  (q=a&3,u=a>>2,c=b&3,v=b>>2)
__global__ __launch_bounds__(256) void k_prep(const float* __restrict__ A,
                                              unsigned short* __restrict__ AbT,
                                              const float* __restrict__ W,
                                              unsigned short* __restrict__ BtT) {
  const int bid = blockIdx.x;
  if (bid < 8192) {
    const int tile = bid >> 2;                       // R*64 + T
    const int t = ((bid & 3) << 8) + threadIdx.x;    // chunk 0..1023
    const int r = t >> 2;
    const int ga = (t & 3) ^ ((r >> 1) & 3);
    const int R = tile >> 6, T = tile & 63;
    const float* src = A + (size_t)(R * 256 + r) * IN_F + T * 32 + ga * 8;
    const float4 v0 = *reinterpret_cast<const float4*>(src);
    const float4 v1 = *reinterpret_cast<const float4*>(src + 4);
    ushortx8 o;
    o[0] = f2bf(v0.x); o[1] = f2bf(v0.y); o[2] = f2bf(v0.z); o[3] = f2bf(v0.w);
    o[4] = f2bf(v1.x); o[5] = f2bf(v1.y); o[6] = f2bf(v1.z); o[7] = f2bf(v1.w);
    *reinterpret_cast<ushortx8*>(AbT + (size_t)tile * 8192 + t * 8) = o;
  } else {
    const int bb = bid - 8192;                       // 0..2047
    const int tile = bb >> 2;                        // Ct*64 + T, 0..511
    const int t = ((bb & 3) << 8) + threadIdx.x;
    const int r = t >> 2;
    const int ga = (t & 3) ^ ((r >> 1) & 3);
    const int Ct = tile >> 6, T = tile & 63;
    const int b = Ct * 256 + r;
    const int c = b & 3, v = b >> 2;
    const int a0 = T * 32 + ga * 8;
    ushortx8 o;
#pragma unroll
    for (int e = 0; e < 8; ++e) {
      const int a = a0 + e;
      const int q = a & 3, u = a >> 2;
      float w = W[(size_t)u * OUT_F + ((q ^ c) << 9) + v];
      if ((0x284E >> ((q << 2) | c)) & 1) w = -w;
      o[e] = f2bf(w);
    }
    *reinterpret_cast<ushortx8*>(BtT + (size_t)tile * 8192 + t * 8) = o;
  }
}

// ---- main GEMM: C = A(bf16) @ Ht^T + bias. r2 schedule, linear staging. ----
__global__ __launch_bounds__(512, 2) void k_gemm(const unsigned short* __restrict__ AbT,
                                                 const unsigned short* __restrict__ BtT,
                                                 const float* __restrict__ bias,
                                                 float* __restrict__ C) {
  __shared__ __align__(16) unsigned short lds[4 * BUF_SHORTS];  // 128 KiB

  const int tid = threadIdx.x;
  const int lane = tid & 63;
  const int w = tid >> 6;   // wave 0..7
  const int wm = w >> 2;    // 0..1 -> rows wm*128..+128
  const int wn = w & 3;     // 0..3 -> cols wn*64..+64
  const int fr = lane & 15;
  const int g = lane >> 4;  // k-group 0..3 (8 bf16 each)

  // XCD-bijective swizzle: 256 wgs, 32 contiguous tiles per XCD
  const int wg = blockIdx.x;
  const int swz = (wg & 7) * (NWG >> 3) + (wg >> 3);
  const int tm = swz >> 3;
  const int tn = swz & 7;
  const int row0 = tm * BM, col0 = tn * BN;

  // ---- staging: sources are pre-tiled images -> fully linear.
  // Per wave: 2 A-instrs + 2 B-instrs, each 1 KB contiguous.
  const unsigned short* baseA = AbT + (size_t)tm * 64 * 8192;
  const unsigned short* baseB = BtT + (size_t)tn * 64 * 8192;
  const int tOff0 = (w * 128 + lane) * 8;        // shorts
  const int tOff1 = (w * 128 + 64 + lane) * 8;

#define STAGE(T)                                                   \
  do {                                                             \
    unsigned short* base_ = &lds[((T) & 3) * BUF_SHORTS];          \
    const unsigned short* sa_ = baseA + (size_t)(T) * 8192;        \
    const unsigned short* sb_ = baseB + (size_t)(T) * 8192;        \
    async16(base_ + tOff0, sa_ + tOff0);                           \
    async16(base_ + tOff1, sa_ + tOff1);                           \
    async16(base_ + TILE_SHORTS + tOff0, sb_ + tOff0);             \
    async16(base_ + TILE_SHORTS + tOff1, sb_ + tOff1);             \
  } while (0)

  // ---- fragment read offsets (shorts), read-side swizzle = baked swizzle
  int offA[8], offB[4];
#pragma unroll
  for (int m = 0; m < 8; ++m) {
    const int r = wm * 128 + m * 16 + fr;
    offA[m] = r * BK + ((g ^ ((r >> 1) & 3)) << 3);
  }
#pragma unroll
  for (int n = 0; n < 4; ++n) {
    const int r = wn * 64 + n * 16 + fr;
    offB[n] = TILE_SHORTS + r * BK + ((g ^ ((r >> 1) & 3)) << 3);
  }

  f32x4 acc[8][4] = {};

#define MFMA_(a_, b_, c_) __builtin_amdgcn_mfma_f32_16x16x32_bf16(a_, b_, c_, 0, 0, 0)

  // prologue: 3 tiles in flight (12 loads/wave)
  STAGE(0);
  STAGE(1);
  STAGE(2);

  // Per K-step (r2 schedule): vmcnt(N) [stage T retired] -> barrier ->
  // 12 ds_reads -> STAGE(T+3) -> 32 MFMA.
#define TILE(T, VMSTR, DOSTAGE)                                               \
  do {                                                                        \
    asm volatile("s_waitcnt vmcnt(" VMSTR ")" ::: "memory");                  \
    __builtin_amdgcn_s_barrier();                                             \
    __builtin_amdgcn_sched_barrier(0);                                        \
    const unsigned short* b_ = &lds[((T) & 3) * BUF_SHORTS];                  \
    bf16x8 bg[4], af[8];                                                      \
    _Pragma("unroll") for (int n = 0; n < 4; ++n) bg[n] = ld8(b_ + offB[n]);  \
    _Pragma("unroll") for (int m = 0; m < 8; ++m) af[m] = ld8(b_ + offA[m]);  \
    if (DOSTAGE) STAGE((T) + 3);                                              \
    __builtin_amdgcn_s_setprio(1);                                            \
    _Pragma("unroll") for (int m = 0; m < 8; ++m)                             \
      _Pragma("unroll") for (int n = 0; n < 4; ++n)                           \
        acc[m][n] = MFMA_(af[m], bg[n], acc[m][n]);                           \
    __builtin_amdgcn_s_setprio(0);                                            \
  } while (0)

  for (int t = 0; t < NT - 3; ++t) {
    TILE(t, "8", true);
  }
  TILE(NT - 3, "8", false);
  TILE(NT - 2, "4", false);
  TILE(NT - 1, "0", false);

#undef TILE
#undef STAGE

  // ---- epilogue: C/D layout col=lane&15, row=(lane>>4)*4+reg ----
  const int g4 = g << 2;
  float bv[4];
#pragma unroll
  for (int n = 0; n < 4; ++n) bv[n] = bias[col0 + wn * 64 + n * 16 + fr];
#pragma unroll
  for (int m = 0; m < 8; ++m) {
#pragma unroll
    for (int e = 0; e < 4; ++e) {
      const int row = row0 + wm * 128 + m * 16 + g4 + e;
      float* cp = C + (size_t)row * OUT_F + col0 + wn * 64 + fr;
#pragma unroll
      for (int n = 0; n < 4; ++n) cp[n * 16] = acc[m][n][e] + bv[n];
    }
  }
}

// ---- fallback if workspace too small: naive fp32 ----
__global__ __launch_bounds__(256) void k_naive(const float* __restrict__ A,
                                               const float* __restrict__ W,
                                               const float* __restrict__ bias,
                                               float* __restrict__ C) {
  const int idx = blockIdx.x * 256 + threadIdx.x;
  const int m = idx >> 11;
  const int b = idx & (OUT_F - 1);
  const int c = b & 3, v = b >> 2;
  float acc = 0.f;
  const float* arow = A + (size_t)m * IN_F;
  for (int a = 0; a < IN_F; ++a) {
    const int q = a & 3, u = a >> 2;
    float h = W[(size_t)u * OUT_F + ((q ^ c) << 9) + v];
    if ((0x284E >> ((q << 2) | c)) & 1) h = -h;
    acc += arow[a] * h;
  }
  C[idx] = acc + bias[b];
}

extern "C" void kernel_launch(void* const* d_in, const int* in_sizes, int n_in,
                              void* d_out, int out_size, void* d_ws, size_t ws_size,
                              hipStream_t stream) {
  (void)in_sizes; (void)n_in; (void)out_size;
  const float* inp  = (const float*)d_in[0];
  const float* w    = (const float*)d_in[1];
  const float* bias = (const float*)d_in[2];
  float* out = (float*)d_out;

  const size_t needA = (size_t)N_ROWS * IN_F * sizeof(unsigned short);  // 32 MiB
  const size_t needH = (size_t)IN_F * OUT_F * sizeof(unsigned short);   //  8 MiB
  if (ws_size < needA + needH) {
    k_naive<<<(N_ROWS * OUT_F) / 256, 256, 0, stream>>>(inp, w, bias, out);
    return;
  }

  unsigned short* AbT = (unsigned short*)d_ws;
  unsigned short* BtT = AbT + (size_t)N_ROWS * IN_F;

  k_prep<<<8192 + 2048, 256, 0, stream>>>(inp, AbT, w, BtT);
  k_gemm<<<NWG, 512, 0, stream>>>(AbT, BtT, bias, out);
}